// Round 2
// baseline (310.814 us; speedup 1.0000x reference)
//
#include <hip/hip_runtime.h>
#include <stdint.h>

// B=16, S=2048, D=128 attention, per-query scale folded into Q (with log2e),
// online softmax in exp2 domain, exact JAX partitionable-threefry dropout
// (key 42, p=0.1), @V.
// Round 8 (verified 276.7us): fat tile TQ=128 + double-buffered K/V LDS,
// single barrier/iter, 3-stage register prefetch, threefry in MFMA shadow.
// Round 10: TQ 128->64, 256 threads (2 q-groups x 2 key-phases), grid 512
// blocks = 2 blocks/CU (was 1).  Theory: 1-block lockstep leaves the VALU
// idle during MFMA phases + barrier drain; a second independent block per
// CU fills those holes.  LDS 81920B = exactly 2 blocks in 160KiB.
// Per-wave structure (2 q-subtiles, shared K-frags, wave-private P) is
// unchanged; per-thread staging doubles (32+32 floats in flight).

#define B_ 16
#define S_ 2048
#define D_ 128
#define TQ 64     // q rows per block (2 groups x 32)
#define TK 64     // keys staged per iteration (each kph-wave consumes 32)
#define NT (S_ / TK)
#define KSTR 136  // f16 stride for K rows (128+8): 272B, 16B-aligned, 2-way banks
#define VSTR 72   // f16 stride for V^T rows (64+8): 144B
#define PSTR 40   // f16 stride for per-wave P rows (32+8): 80B

typedef float f32x4 __attribute__((ext_vector_type(4)));
typedef _Float16 f16x8 __attribute__((ext_vector_type(8)));
typedef _Float16 f16x2 __attribute__((ext_vector_type(2)));

union F32R8 { float4 q[8]; float f[32]; };

// DPP row_ror reductions over 16-lane row groups.
#define DPP_ROR(x, ctrl) \
  __int_as_float(__builtin_amdgcn_update_dpp(0, __float_as_int(x), (ctrl), 0xf, 0xf, true))
__device__ __forceinline__ float row16_max(float x) {
  x = fmaxf(x, DPP_ROR(x, 0x128));
  x = fmaxf(x, DPP_ROR(x, 0x124));
  x = fmaxf(x, DPP_ROR(x, 0x122));
  x = fmaxf(x, DPP_ROR(x, 0x121));
  return x;
}
__device__ __forceinline__ float row16_sum(float x) {
  x += DPP_ROR(x, 0x128);
  x += DPP_ROR(x, 0x124);
  x += DPP_ROR(x, 0x122);
  x += DPP_ROR(x, 0x121);
  return x;
}

// threefry2x32, 20 rounds, key = (0, 42)  [jax.random.key(42)]
__device__ __forceinline__ uint2 threefry2x32_0_42(uint32_t x0, uint32_t x1) {
  const uint32_t k0 = 0u, k1 = 42u;
  const uint32_t k2 = 0x1BD11BDAu ^ k0 ^ k1;
  x0 += k0; x1 += k1;
#define TFR(r) { x0 += x1; x1 = __builtin_rotateleft32(x1, r); x1 ^= x0; }
  TFR(13) TFR(15) TFR(26) TFR(6)
  x0 += k1; x1 += k2 + 1u;
  TFR(17) TFR(29) TFR(16) TFR(24)
  x0 += k2; x1 += k0 + 2u;
  TFR(13) TFR(15) TFR(26) TFR(6)
  x0 += k0; x1 += k1 + 3u;
  TFR(17) TFR(29) TFR(16) TFR(24)
  x0 += k1; x1 += k2 + 4u;
  TFR(13) TFR(15) TFR(26) TFR(6)
  x0 += k2; x1 += k0 + 5u;
#undef TFR
  return make_uint2(x0, x1);
}

// HW-verified (round 2): partitionable path, counter (0, j), xor-fold.
__device__ __forceinline__ uint32_t jax_bits(uint32_t j) {
  const uint2 tf = threefry2x32_0_42(0u, j);
  return tf.x ^ tf.y;
}

__global__ __launch_bounds__(256, 2)
void attn_mfma_kernel(const float* __restrict__ Q, const float* __restrict__ K,
                      const float* __restrict__ V, const float* __restrict__ ISF,
                      const float* __restrict__ DP, float* __restrict__ OUT) {
  extern __shared__ __align__(16) char smem[];
  _Float16* const sK0  = (_Float16*)smem;               // 64x136 f16 = 17408 B
  _Float16* const sK1  = (_Float16*)(smem + 17408);
  _Float16* const sVT0 = (_Float16*)(smem + 34816);     // 128x72 f16 = 18432 B
  _Float16* const sVT1 = (_Float16*)(smem + 53248);
  _Float16* const sP   = (_Float16*)(smem + 71680);     // 4 x 32x40 = 10240 B
  // merge overlay (after final barrier):
  float* const sO1 = (float*)smem;                      // 64x128 f32 = 32768 B
  float* const sM1 = (float*)(smem + 32768);            // 64 f32
  float* const sL1 = (float*)(smem + 33024);            // 64 f32

  const int t    = threadIdx.x;
  const int lane = t & 63;
  const int l15  = lane & 15;
  const int quad = lane >> 4;
  const int w    = t >> 6;       // 0..3
  const int qg   = w & 1;        // q-group (32 rows)
  const int kph  = w >> 1;       // key phase: 0 = keys [0,32), 1 = [32,64)
  const int b    = blockIdx.y;
  const int qb   = blockIdx.x * TQ + qg * 32;

  const float kp = 1.0f - DP[0];
  const uint32_t TH9 = (__float_as_uint(1.0f + kp) & 0x7FFFFFu) << 9;

  float m_[2][4], l_[2][4];
  uint32_t jq[2][4];
  #pragma unroll
  for (int sub = 0; sub < 2; ++sub)
    #pragma unroll
    for (int r = 0; r < 4; ++r) {
      m_[sub][r] = -INFINITY;
      l_[sub][r] = 0.0f;
      jq[sub][r] = ((uint32_t)b << 22)
                 + (uint32_t)(qb + sub * 16 + quad * 4 + r) * (uint32_t)S_;
    }

  // ---- Q fragments (2 subtiles), f16, 1/isf and log2(e) folded in ----
  f16x8 qf[2][4];
  #pragma unroll
  for (int sub = 0; sub < 2; ++sub) {
    const int qrow = qb + sub * 16 + l15;
    const float qs = 1.4426950408889634f / ISF[b * S_ + qrow];
    const float* qp = Q + ((size_t)(b * S_ + qrow)) * D_;
    #pragma unroll
    for (int c = 0; c < 4; ++c) {
      const float4 a  = *(const float4*)(qp + c * 32 + quad * 8);
      const float4 d2 = *(const float4*)(qp + c * 32 + quad * 8 + 4);
      const float xs[8] = {a.x, a.y, a.z, a.w, d2.x, d2.y, d2.z, d2.w};
      f16x8 h;
      #pragma unroll
      for (int j = 0; j < 8; ++j) h[j] = (_Float16)(xs[j] * qs);
      qf[sub][c] = h;
    }
  }

  f32x4 accO[2][8];
  #pragma unroll
  for (int sub = 0; sub < 2; ++sub)
    #pragma unroll
    for (int i = 0; i < 8; ++i) accO[sub][i] = (f32x4){0.f, 0.f, 0.f, 0.f};

  _Float16* const pwv = &sP[w * 32 * PSTR];

  // staging decomposition (256 threads)
  const int krow = t >> 2, kcol = (t & 3) * 32;        // K: 64 rows x 128
  const int vp = t & 31, dseg = (t >> 5) * 16;         // V: 32 key-pairs x 16 d

  F32R8 kreg;           // prefetched K floats (32/thread)
  F32R8 vreg;           // prefetched V floats (16+16/thread)

#define ISSUE_LOADS(KT)                                                        \
  {                                                                            \
    const float4* gk4 = (const float4*)(K +                                    \
        ((size_t)(b * S_ + (KT) * TK + krow)) * D_ + kcol);                    \
    _Pragma("unroll") for (int i = 0; i < 8; ++i) kreg.q[i] = gk4[i];          \
    const float4* gv4 = (const float4*)(V +                                    \
        ((size_t)(b * S_ + (KT) * TK + 2 * vp)) * D_ + dseg);                  \
    _Pragma("unroll") for (int i = 0; i < 4; ++i) {                            \
      vreg.q[i] = gv4[i];                                                      \
      vreg.q[i + 4] = gv4[i + 32];  /* +128 floats = next key row */           \
    }                                                                          \
  }

#define CONVERT_TO(KB, VB)                                                     \
  {                                                                            \
    _Pragma("unroll") for (int g = 0; g < 4; ++g) {                            \
      f16x8 h;                                                                 \
      _Pragma("unroll") for (int j = 0; j < 8; ++j)                            \
        h[j] = (_Float16)kreg.f[g * 8 + j];                                    \
      *(f16x8*)&(KB)[krow * KSTR + kcol + g * 8] = h;                          \
    }                                                                          \
    _Pragma("unroll") for (int d = 0; d < 16; ++d) {                           \
      f16x2 h = {(_Float16)vreg.f[d], (_Float16)vreg.f[16 + d]};               \
      *(f16x2*)&(VB)[(dseg + d) * VSTR + 2 * vp] = h;                          \
    }                                                                          \
  }

  // ---- pipeline prologue: tile 0 -> buf0; issue loads for tile 1 ----
  ISSUE_LOADS(0)
  CONVERT_TO(sK0, sVT0)
  ISSUE_LOADS(1)
  __syncthreads();

  for (int kt = 0; kt < NT; ++kt) {
    const int cur = kt & 1;
    _Float16* const sKc = cur ? sK1 : sK0;
    _Float16* const sVc = cur ? sVT1 : sVT0;

    // ---- QK^T: 2 q-subtiles x 32 keys; K-frags shared across subtiles ----
    f32x4 s[2][2];
    #pragma unroll
    for (int n = 0; n < 2; ++n) {
      f32x4 a0 = (f32x4){0.f, 0.f, 0.f, 0.f};
      f32x4 a1 = (f32x4){0.f, 0.f, 0.f, 0.f};
      #pragma unroll
      for (int c = 0; c < 4; ++c) {
        const f16x8 bh = *(const f16x8*)&sKc[(kph * 32 + n * 16 + l15) * KSTR
                                             + c * 32 + quad * 8];
        a0 = __builtin_amdgcn_mfma_f32_16x16x32_f16(qf[0][c], bh, a0, 0, 0, 0);
        a1 = __builtin_amdgcn_mfma_f32_16x16x32_f16(qf[1][c], bh, a1, 0, 0, 0);
      }
      s[0][n] = a0;
      s[1][n] = a1;
    }

    // ---- dropout bits (independent of scores; schedules into MFMA shadow) ----
    uint32_t rb[2][2][4];
    #pragma unroll
    for (int sub = 0; sub < 2; ++sub)
      #pragma unroll
      for (int n = 0; n < 2; ++n) {
        const uint32_t jcol = (uint32_t)(kt * TK + kph * 32 + n * 16 + l15);
        #pragma unroll
        for (int r = 0; r < 4; ++r)
          rb[sub][n][r] = jax_bits(jq[sub][r] + jcol);
      }

    // ---- online softmax (exp2 domain), per subtile ----
    float mx[2][4];
    int changed = 0;
    #pragma unroll
    for (int sub = 0; sub < 2; ++sub)
      #pragma unroll
      for (int r = 0; r < 4; ++r) {
        mx[sub][r] = row16_max(fmaxf(s[sub][0][r], s[sub][1][r]));
        changed |= (mx[sub][r] > m_[sub][r]);
      }
    if (__ballot(changed) != 0ull) {
      #pragma unroll
      for (int sub = 0; sub < 2; ++sub)
        #pragma unroll
        for (int r = 0; r < 4; ++r) {
          const float mnew = fmaxf(m_[sub][r], mx[sub][r]);
          const float alpha = __builtin_amdgcn_exp2f(m_[sub][r] - mnew);
          m_[sub][r] = mnew;
          l_[sub][r] *= alpha;
          #pragma unroll
          for (int i = 0; i < 8; ++i) accO[sub][i][r] *= alpha;
        }
    }
    #pragma unroll
    for (int sub = 0; sub < 2; ++sub)
      #pragma unroll
      for (int r = 0; r < 4; ++r) {
        const float p0 = __builtin_amdgcn_exp2f(s[sub][0][r] - m_[sub][r]);
        const float p1 = __builtin_amdgcn_exp2f(s[sub][1][r] - m_[sub][r]);
        s[sub][0][r] = p0;
        s[sub][1][r] = p1;
        l_[sub][r] += row16_sum(p0 + p1);
      }

    // ---- masked f16 P into wave-private LDS ----
    #pragma unroll
    for (int sub = 0; sub < 2; ++sub)
      #pragma unroll
      for (int n = 0; n < 2; ++n) {
        const int col = n * 16 + l15;
        #pragma unroll
        for (int r = 0; r < 4; ++r) {
          const float pf = (rb[sub][n][r] < TH9) ? s[sub][n][r] : 0.0f;
          pwv[(sub * 16 + quad * 4 + r) * PSTR + col] = (_Float16)pf;
        }
      }
    __threadfence_block();   // order cross-lane P writes before A-frag reads

    // ---- PV: per subtile O[16x128] += P[16x32] * V[32x128]; V shared ----
    {
      const f16x8 ap0 = *(const f16x8*)&pwv[l15 * PSTR + quad * 8];
      const f16x8 ap1 = *(const f16x8*)&pwv[(16 + l15) * PSTR + quad * 8];
      #pragma unroll
      for (int d8 = 0; d8 < 8; ++d8) {
        const f16x8 bv = *(const f16x8*)&sVc[(d8 * 16 + l15) * VSTR
                                             + kph * 32 + quad * 8];
        accO[0][d8] = __builtin_amdgcn_mfma_f32_16x16x32_f16(ap0, bv, accO[0][d8], 0, 0, 0);
        accO[1][d8] = __builtin_amdgcn_mfma_f32_16x16x32_f16(ap1, bv, accO[1][d8], 0, 0, 0);
      }
    }

    // ---- pipeline advance: convert kt+1 into the other buffer, then
    //      issue loads for kt+2.  Safe: buf[(kt+1)&1] readers finished at
    //      the barrier ending iter kt-1. ----
    if (kt + 1 < NT) {
      _Float16* const sKn = cur ? sK0 : sK1;
      _Float16* const sVn = cur ? sVT0 : sVT1;
      CONVERT_TO(sKn, sVn)
      if (kt + 2 < NT) ISSUE_LOADS(kt + 2)
    }
    __syncthreads();   // single barrier per iteration
  }
#undef ISSUE_LOADS
#undef CONVERT_TO

  // ---- merge the two key-phase waves of each q-group ----
  if (kph == 1) {
    #pragma unroll
    for (int sub = 0; sub < 2; ++sub) {
      if (l15 == 0) {
        #pragma unroll
        for (int r = 0; r < 4; ++r) {
          const int gr = qg * 32 + sub * 16 + quad * 4 + r;
          sM1[gr] = m_[sub][r];
          sL1[gr] = l_[sub][r];
        }
      }
      #pragma unroll
      for (int d8 = 0; d8 < 8; ++d8)
        #pragma unroll
        for (int r = 0; r < 4; ++r) {
          const int gr = qg * 32 + sub * 16 + quad * 4 + r;
          sO1[gr * D_ + d8 * 16 + l15] = accO[sub][d8][r];
        }
    }
  }
  __syncthreads();
  if (kph == 0) {
    #pragma unroll
    for (int sub = 0; sub < 2; ++sub) {
      float a0s[4], a1s[4];
      #pragma unroll
      for (int r = 0; r < 4; ++r) {
        const int gr = qg * 32 + sub * 16 + quad * 4 + r;
        const float m1  = sM1[gr];
        const float l1v = sL1[gr];
        const float mf = fmaxf(m_[sub][r], m1);
        const float a0 = __builtin_amdgcn_exp2f(m_[sub][r] - mf);
        const float a1 = __builtin_amdgcn_exp2f(m1 - mf);
        const float inv = 1.0f / ((a0 * l_[sub][r] + a1 * l1v) * kp);
        a0s[r] = a0 * inv;
        a1s[r] = a1 * inv;
      }
      #pragma unroll
      for (int d8 = 0; d8 < 8; ++d8)
        #pragma unroll
        for (int r = 0; r < 4; ++r) {
          const int gr = qg * 32 + sub * 16 + quad * 4 + r;
          const float o1 = sO1[gr * D_ + d8 * 16 + l15];
          OUT[((size_t)(b * S_ + blockIdx.x * TQ + gr)) * D_ + d8 * 16 + l15] =
              accO[sub][d8][r] * a0s[r] + o1 * a1s[r];
        }
    }
  }
}

extern "C" void kernel_launch(void* const* d_in, const int* in_sizes, int n_in,
                              void* d_out, int out_size, void* d_ws, size_t ws_size,
                              hipStream_t stream) {
  const float* q   = (const float*)d_in[0];
  const float* k   = (const float*)d_in[1];
  const float* v   = (const float*)d_in[2];
  const float* isf = (const float*)d_in[3];
  const float* dp  = (const float*)d_in[4];
  float* out = (float*)d_out;

  dim3 grid(S_ / TQ, B_);
  attn_mfma_kernel<<<grid, dim3(256), 81920, stream>>>(q, k, v, isf, dp, out);
}